// Round 1
// baseline (180.288 us; speedup 1.0000x reference)
//
#include <hip/hip_runtime.h>
#include <hip/hip_bf16.h>

typedef __attribute__((ext_vector_type(8))) short short8;
typedef __attribute__((ext_vector_type(4))) float f32x4;
typedef unsigned short u16;

__device__ __forceinline__ u16 f2bf(float f) {
  __hip_bfloat16 h = __float2bfloat16(f);
  return __builtin_bit_cast(unsigned short, h);
}

__device__ __forceinline__ void gload16(const u16* g, u16* l) {
  __builtin_amdgcn_global_load_lds(
      (const __attribute__((address_space(1))) unsigned int*)g,
      (__attribute__((address_space(3))) unsigned int*)l, 16, 0, 0);
}

// ---------- x fp32 -> bf16 ----------
__global__ void cvt_x_kernel(const float* __restrict__ in, u16* __restrict__ out, int n) {
  int i = (blockIdx.x * blockDim.x + threadIdx.x) * 4;
  if (i >= n) return;
  float4 f = *(const float4*)(in + i);
  uint2 pk;
  pk.x = (unsigned)f2bf(f.x) | ((unsigned)f2bf(f.y) << 16);
  pk.y = (unsigned)f2bf(f.z) | ((unsigned)f2bf(f.w) << 16);
  *(uint2*)(out + i) = pk;
}

// ---------- W [1024][N] fp32 -> Wt [N][1024] bf16 ----------
__global__ void tcvt_kernel(const float* __restrict__ in, u16* __restrict__ out, int N) {
  __shared__ float tile[32][33];
  int n0 = blockIdx.x * 32, k0 = blockIdx.y * 32;
  int tx = threadIdx.x, ty = threadIdx.y;  // 32 x 8
#pragma unroll
  for (int r = 0; r < 4; ++r) {
    int k = ty + r * 8;
    tile[k][tx] = in[(size_t)(k0 + k) * N + n0 + tx];
  }
  __syncthreads();
#pragma unroll
  for (int r = 0; r < 4; ++r) {
    int n = ty + r * 8;
    out[(size_t)(n0 + n) * 1024 + k0 + tx] = f2bf(tile[tx][n]);
  }
}

// ---------- GEMM: C[128x128 tile] = A[M][1024] * Bt[N][1024]^T + bias ----------
// EPI 0: scatter to QKV bf16 [3][b][h][s][64], Q scaled by 0.125
// EPI 1: fp32 out [4096][1024] + bias
template <int EPI>
__global__ __launch_bounds__(256, 2) void gemm_kernel(const u16* __restrict__ A,
                                                      const u16* __restrict__ Bt,
                                                      const float* __restrict__ bias,
                                                      void* __restrict__ outp) {
  __shared__ u16 Al[128 * 64];
  __shared__ u16 Bl[128 * 64];
  const int tid = threadIdx.x;
  const int lane = tid & 63, wid = tid >> 6;
  const int l15 = lane & 15, lg = lane >> 4;
  const int wm = wid >> 1, wn = wid & 1;
  const int m0 = blockIdx.y * 128, n0 = blockIdx.x * 128;

  f32x4 acc[4][4] = {};

  for (int k0 = 0; k0 < 1024; k0 += 64) {
    __syncthreads();
#pragma unroll
    for (int i = 0; i < 4; ++i) {
      int p = i * 4096 + tid * 16;
      int row = p >> 7;                         // tile row (128B per row)
      int lslot = ((p >> 4) & 7) ^ (row & 7);   // source pre-swizzle (T2)
      gload16(A + (size_t)(m0 + row) * 1024 + k0 + lslot * 8, Al + i * 2048 + wid * 512);
      gload16(Bt + (size_t)(n0 + row) * 1024 + k0 + lslot * 8, Bl + i * 2048 + wid * 512);
    }
    __syncthreads();
#pragma unroll
    for (int ks = 0; ks < 2; ++ks) {
      short8 af[4], bfr[4];
#pragma unroll
      for (int m = 0; m < 4; ++m) {
        int row = wm * 64 + m * 16 + l15;
        af[m] = *(const short8*)((const char*)Al + row * 128 + (((ks * 4 + lg) ^ (row & 7)) << 4));
      }
#pragma unroll
      for (int n = 0; n < 4; ++n) {
        int row = wn * 64 + n * 16 + l15;
        bfr[n] = *(const short8*)((const char*)Bl + row * 128 + (((ks * 4 + lg) ^ (row & 7)) << 4));
      }
#pragma unroll
      for (int m = 0; m < 4; ++m)
#pragma unroll
        for (int n = 0; n < 4; ++n)
          acc[m][n] = __builtin_amdgcn_mfma_f32_16x16x32_bf16(af[m], bfr[n], acc[m][n], 0, 0, 0);
    }
  }

  if (EPI == 0) {
    u16* qkv = (u16*)outp;
#pragma unroll
    for (int m = 0; m < 4; ++m)
#pragma unroll
      for (int n = 0; n < 4; ++n) {
        const int gcol = n0 + wn * 64 + n * 16 + l15;
        const int which = gcol >> 10, dd = gcol & 1023;
        const int h = dd >> 6, hd = dd & 63;
        const float bb = bias[gcol];
#pragma unroll
        for (int j = 0; j < 4; ++j) {
          const int grow = m0 + wm * 64 + m * 16 + lg * 4 + j;
          const int b = grow >> 11, s = grow & 2047;
          float v = acc[m][n][j] + bb;
          if (which == 0) v *= 0.125f;  // fold 1/sqrt(64) into Q
          qkv[(size_t)which * 4194304 + ((size_t)(b * 16 + h) * 2048 + s) * 64 + hd] = f2bf(v);
        }
      }
  } else {
    float* O = (float*)outp;
#pragma unroll
    for (int m = 0; m < 4; ++m)
#pragma unroll
      for (int n = 0; n < 4; ++n) {
        const int gcol = n0 + wn * 64 + n * 16 + l15;
        const float bb = bias[gcol];
#pragma unroll
        for (int j = 0; j < 4; ++j) {
          const int grow = m0 + wm * 64 + m * 16 + lg * 4 + j;
          O[(size_t)grow * 1024 + gcol] = acc[m][n][j] + bb;
        }
      }
  }
}

// ---------- causal flash attention: Q,K,V bf16 [b*h][2048][64] -> Attn bf16 [b][s][h*64] ----------
__global__ __launch_bounds__(256, 2) void attn_kernel(const u16* __restrict__ Q,
                                                      const u16* __restrict__ K,
                                                      const u16* __restrict__ V,
                                                      u16* __restrict__ Aout) {
  const int bh = blockIdx.y;        // 0..31
  const int qb = blockIdx.x;        // 0..15
  const int qbase = qb * 128;
  const int tid = threadIdx.x, lane = tid & 63, wid = tid >> 6;
  const int l15 = lane & 15, lg = lane >> 4;
  const int qw = qbase + wid * 32;  // wave's first q row

  __shared__ u16 Kl[64 * 64];       // [kv][hd], source-swizzled
  __shared__ u16 Vt[64 * 68];       // [hd][kv], padded stride 68
  __shared__ u16 Pl[4][32 * 68];    // per-wave P, padded stride 68

  const u16* Qb = Q + (size_t)bh * 2048 * 64;
  const u16* Kb = K + (size_t)bh * 2048 * 64;
  const u16* Vb = V + (size_t)bh * 2048 * 64;

  // Q fragments (already scaled by 0.125 in QKV epilogue)
  short8 qf[2][2];
#pragma unroll
  for (int m = 0; m < 2; ++m)
#pragma unroll
    for (int ks = 0; ks < 2; ++ks)
      qf[m][ks] = *(const short8*)(Qb + (size_t)(qw + m * 16 + l15) * 64 + ks * 32 + lg * 8);

  f32x4 acc_o[2][4] = {};
  float mrun[2][4], lrun[2][4];
#pragma unroll
  for (int m = 0; m < 2; ++m)
#pragma unroll
    for (int j = 0; j < 4; ++j) { mrun[m][j] = -1e30f; lrun[m][j] = 0.f; }

  const int ntiles = qb * 2 + 2;
  for (int t = 0; t < ntiles; ++t) {
    __syncthreads();
    const int kvb = t * 64;
    // stage K tile [64][64] via global_load_lds, source pre-swizzled
#pragma unroll
    for (int i = 0; i < 2; ++i) {
      int p = i * 4096 + tid * 16;
      int row = p >> 7;
      int lslot = ((p >> 4) & 7) ^ (row & 7);
      gload16(Kb + (size_t)(kvb + row) * 64 + lslot * 8, Kl + i * 2048 + wid * 512);
    }
    // stage V transposed: coalesced 16B reads, scalar LDS writes
#pragma unroll
    for (int i = 0; i < 2; ++i) {
      int r = i * 32 + (tid >> 3);
      int c = (tid & 7) * 8;
      short8 v = *(const short8*)(Vb + (size_t)(kvb + r) * 64 + c);
#pragma unroll
      for (int j = 0; j < 8; ++j) Vt[(c + j) * 68 + r] = (u16)(unsigned short)v[j];
    }
    __syncthreads();

    if (kvb <= qw + 31) {  // wave-uniform: this wave has unmasked work in this tile
      const bool need_mask = (kvb + 63) > qw;
      short8 kf[4][2];
#pragma unroll
      for (int n = 0; n < 4; ++n)
#pragma unroll
        for (int ks = 0; ks < 2; ++ks) {
          int row = n * 16 + l15;
          kf[n][ks] = *(const short8*)((const char*)Kl + row * 128 + (((ks * 4 + lg) ^ (row & 7)) << 4));
        }
#pragma unroll
      for (int m = 0; m < 2; ++m) {
        f32x4 sa[4] = {};
#pragma unroll
        for (int n = 0; n < 4; ++n)
#pragma unroll
          for (int ks = 0; ks < 2; ++ks)
            sa[n] = __builtin_amdgcn_mfma_f32_16x16x32_bf16(qf[m][ks], kf[n][ks], sa[n], 0, 0, 0);
        if (need_mask) {
#pragma unroll
          for (int n = 0; n < 4; ++n)
#pragma unroll
            for (int j = 0; j < 4; ++j) {
              int q = qw + m * 16 + lg * 4 + j;
              int kv = kvb + n * 16 + l15;
              if (kv > q) sa[n][j] = -1e30f;
            }
        }
        float rm[4];
#pragma unroll
        for (int j = 0; j < 4; ++j) {
          rm[j] = fmaxf(fmaxf(sa[0][j], sa[1][j]), fmaxf(sa[2][j], sa[3][j]));
          rm[j] = fmaxf(rm[j], __shfl_xor(rm[j], 1));
          rm[j] = fmaxf(rm[j], __shfl_xor(rm[j], 2));
          rm[j] = fmaxf(rm[j], __shfl_xor(rm[j], 4));
          rm[j] = fmaxf(rm[j], __shfl_xor(rm[j], 8));
        }
#pragma unroll
        for (int j = 0; j < 4; ++j) {
          float mnew = fmaxf(mrun[m][j], rm[j]);
          float corr = __expf(mrun[m][j] - mnew);
          mrun[m][j] = mnew;
          lrun[m][j] *= corr;
#pragma unroll
          for (int n = 0; n < 4; ++n) acc_o[m][n][j] *= corr;
        }
        float rs[4] = {0.f, 0.f, 0.f, 0.f};
#pragma unroll
        for (int n = 0; n < 4; ++n)
#pragma unroll
          for (int j = 0; j < 4; ++j) {
            float p = __expf(sa[n][j] - mrun[m][j]);
            sa[n][j] = p;
            rs[j] += p;
          }
#pragma unroll
        for (int j = 0; j < 4; ++j) {
          rs[j] += __shfl_xor(rs[j], 1);
          rs[j] += __shfl_xor(rs[j], 2);
          rs[j] += __shfl_xor(rs[j], 4);
          rs[j] += __shfl_xor(rs[j], 8);
          lrun[m][j] += rs[j];
        }
#pragma unroll
        for (int n = 0; n < 4; ++n)
#pragma unroll
          for (int j = 0; j < 4; ++j)
            Pl[wid][(m * 16 + lg * 4 + j) * 68 + n * 16 + l15] = f2bf(sa[n][j]);
      }
      // PV
      short8 vf[4][2];
#pragma unroll
      for (int n = 0; n < 4; ++n)
#pragma unroll
        for (int ks = 0; ks < 2; ++ks)
          vf[n][ks] = *(const short8*)((const char*)Vt + (n * 16 + l15) * 136 + ks * 64 + lg * 16);
#pragma unroll
      for (int m = 0; m < 2; ++m) {
        short8 pf[2];
#pragma unroll
        for (int ks = 0; ks < 2; ++ks)
          pf[ks] = *(const short8*)((const char*)Pl[wid] + (m * 16 + l15) * 136 + ks * 64 + lg * 16);
#pragma unroll
        for (int n = 0; n < 4; ++n)
#pragma unroll
          for (int ks = 0; ks < 2; ++ks)
            acc_o[m][n] = __builtin_amdgcn_mfma_f32_16x16x32_bf16(pf[ks], vf[n][ks], acc_o[m][n], 0, 0, 0);
      }
    }
  }

  const int b = bh >> 4, h = bh & 15;
#pragma unroll
  for (int m = 0; m < 2; ++m)
#pragma unroll
    for (int n = 0; n < 4; ++n)
#pragma unroll
      for (int j = 0; j < 4; ++j) {
        int q = qw + m * 16 + lg * 4 + j;
        float v = acc_o[m][n][j] / lrun[m][j];
        Aout[(size_t)(b * 2048 + q) * 1024 + h * 64 + n * 16 + l15] = f2bf(v);
      }
}

extern "C" void kernel_launch(void* const* d_in, const int* in_sizes, int n_in,
                              void* d_out, int out_size, void* d_ws, size_t ws_size,
                              hipStream_t stream) {
  const float* x = (const float*)d_in[0];
  const float* Wqkv = (const float*)d_in[1];
  const float* bqkv = (const float*)d_in[2];
  const float* Wout = (const float*)d_in[3];
  const float* bout = (const float*)d_in[4];

  char* ws = (char*)d_ws;
  u16* Xb = (u16*)(ws + 0);            // 8,388,608 B  (reused as Attn later)
  u16* WqkvT = (u16*)(ws + 8388608);   // 6,291,456 B
  u16* WoutT = (u16*)(ws + 14680064);  // 2,097,152 B
  u16* QKV = (u16*)(ws + 16777216);    // 25,165,824 B (Q,K,V each 4,194,304 elems)
  u16* Attn = Xb;

  cvt_x_kernel<<<4096, 256, 0, stream>>>(x, Xb, 4194304);
  tcvt_kernel<<<dim3(96, 32), dim3(32, 8), 0, stream>>>(Wqkv, WqkvT, 3072);
  tcvt_kernel<<<dim3(32, 32), dim3(32, 8), 0, stream>>>(Wout, WoutT, 1024);
  gemm_kernel<0><<<dim3(24, 32), 256, 0, stream>>>(Xb, WqkvT, bqkv, QKV);
  attn_kernel<<<dim3(16, 32), 256, 0, stream>>>(QKV, QKV + 4194304, QKV + 8388608, Attn);
  gemm_kernel<1><<<dim3(8, 32), 256, 0, stream>>>(Attn, WoutT, bout, d_out);
}

// Round 2
// 144.334 us; speedup vs baseline: 1.2491x; 1.2491x over previous
//
#include <hip/hip_runtime.h>
#include <hip/hip_bf16.h>

typedef __attribute__((ext_vector_type(8))) short short8;
typedef __attribute__((ext_vector_type(4))) float f32x4;
typedef unsigned short u16;

__device__ __forceinline__ u16 f2bf(float f) {
  __hip_bfloat16 h = __float2bfloat16(f);
  return __builtin_bit_cast(unsigned short, h);
}

__device__ __forceinline__ void gload16(const u16* g, u16* l) {
  __builtin_amdgcn_global_load_lds(
      (const __attribute__((address_space(1))) unsigned int*)g,
      (__attribute__((address_space(3))) unsigned int*)l, 16, 0, 0);
}

// ---------- x fp32 -> bf16 ----------
__global__ void cvt_x_kernel(const float* __restrict__ in, u16* __restrict__ out, int n) {
  int i = (blockIdx.x * blockDim.x + threadIdx.x) * 4;
  if (i >= n) return;
  float4 f = *(const float4*)(in + i);
  uint2 pk;
  pk.x = (unsigned)f2bf(f.x) | ((unsigned)f2bf(f.y) << 16);
  pk.y = (unsigned)f2bf(f.z) | ((unsigned)f2bf(f.w) << 16);
  *(uint2*)(out + i) = pk;
}

// ---------- W [1024][N] fp32 -> Wt [N][1024] bf16 ----------
__global__ void tcvt_kernel(const float* __restrict__ in, u16* __restrict__ out, int N) {
  __shared__ float tile[32][33];
  int n0 = blockIdx.x * 32, k0 = blockIdx.y * 32;
  int tx = threadIdx.x, ty = threadIdx.y;  // 32 x 8
#pragma unroll
  for (int r = 0; r < 4; ++r) {
    int k = ty + r * 8;
    tile[k][tx] = in[(size_t)(k0 + k) * N + n0 + tx];
  }
  __syncthreads();
#pragma unroll
  for (int r = 0; r < 4; ++r) {
    int n = ty + r * 8;
    out[(size_t)(n0 + n) * 1024 + k0 + tx] = f2bf(tile[tx][n]);
  }
}

// ---------- GEMM: C[128x128 tile] = A[M][1024] * Bt[N][1024]^T + bias ----------
// EPI 0: scatter to QKV bf16 [3][b][h][s][64], Q scaled by 0.125*log2(e)
// EPI 1: fp32 out [4096][1024] + bias
template <int EPI>
__global__ __launch_bounds__(256, 2) void gemm_kernel(const u16* __restrict__ A,
                                                      const u16* __restrict__ Bt,
                                                      const float* __restrict__ bias,
                                                      void* __restrict__ outp) {
  __shared__ u16 Al[128 * 64];
  __shared__ u16 Bl[128 * 64];
  const int tid = threadIdx.x;
  const int lane = tid & 63, wid = tid >> 6;
  const int l15 = lane & 15, lg = lane >> 4;
  const int wm = wid >> 1, wn = wid & 1;
  const int m0 = blockIdx.y * 128, n0 = blockIdx.x * 128;

  f32x4 acc[4][4] = {};

  for (int k0 = 0; k0 < 1024; k0 += 64) {
    __syncthreads();
#pragma unroll
    for (int i = 0; i < 4; ++i) {
      int p = i * 4096 + tid * 16;
      int row = p >> 7;                         // tile row (128B per row)
      int lslot = ((p >> 4) & 7) ^ (row & 7);   // source pre-swizzle (T2)
      gload16(A + (size_t)(m0 + row) * 1024 + k0 + lslot * 8, Al + i * 2048 + wid * 512);
      gload16(Bt + (size_t)(n0 + row) * 1024 + k0 + lslot * 8, Bl + i * 2048 + wid * 512);
    }
    __syncthreads();
#pragma unroll
    for (int ks = 0; ks < 2; ++ks) {
      short8 af[4], bfr[4];
#pragma unroll
      for (int m = 0; m < 4; ++m) {
        int row = wm * 64 + m * 16 + l15;
        af[m] = *(const short8*)((const char*)Al + row * 128 + (((ks * 4 + lg) ^ (row & 7)) << 4));
      }
#pragma unroll
      for (int n = 0; n < 4; ++n) {
        int row = wn * 64 + n * 16 + l15;
        bfr[n] = *(const short8*)((const char*)Bl + row * 128 + (((ks * 4 + lg) ^ (row & 7)) << 4));
      }
#pragma unroll
      for (int m = 0; m < 4; ++m)
#pragma unroll
        for (int n = 0; n < 4; ++n)
          acc[m][n] = __builtin_amdgcn_mfma_f32_16x16x32_bf16(af[m], bfr[n], acc[m][n], 0, 0, 0);
    }
  }

  if (EPI == 0) {
    u16* qkv = (u16*)outp;
#pragma unroll
    for (int m = 0; m < 4; ++m)
#pragma unroll
      for (int n = 0; n < 4; ++n) {
        const int gcol = n0 + wn * 64 + n * 16 + l15;
        const int which = gcol >> 10, dd = gcol & 1023;
        const int h = dd >> 6, hd = dd & 63;
        const float bb = bias[gcol];
#pragma unroll
        for (int j = 0; j < 4; ++j) {
          const int grow = m0 + wm * 64 + m * 16 + lg * 4 + j;
          const int b = grow >> 11, s = grow & 2047;
          float v = acc[m][n][j] + bb;
          if (which == 0) v *= 0.18033688011112042f;  // 1/sqrt(64) * log2(e)
          qkv[(size_t)which * 4194304 + ((size_t)(b * 16 + h) * 2048 + s) * 64 + hd] = f2bf(v);
        }
      }
  } else {
    float* O = (float*)outp;
#pragma unroll
    for (int m = 0; m < 4; ++m)
#pragma unroll
      for (int n = 0; n < 4; ++n) {
        const int gcol = n0 + wn * 64 + n * 16 + l15;
        const float bb = bias[gcol];
#pragma unroll
        for (int j = 0; j < 4; ++j) {
          const int grow = m0 + wm * 64 + m * 16 + lg * 4 + j;
          O[(size_t)grow * 1024 + gcol] = acc[m][n][j] + bb;
        }
      }
  }
}

// ---------- causal flash attention ----------
// Grid (8, 32). Block = 512 threads (8 waves). Block qp handles q-tiles qp and
// 15-qp (complement pairing -> exactly 34 tile-units of compute per block).
// Wave w owns 16-row strips: rows qX*128 + w*16 of each q-tile.
// KV tiles double-buffered; next tile prefetched before computing current.
__global__ __launch_bounds__(512, 2) void attn_kernel(const u16* __restrict__ Q,
                                                      const u16* __restrict__ K,
                                                      const u16* __restrict__ V,
                                                      u16* __restrict__ Aout) {
  const int bh = blockIdx.y;   // 0..31
  const int qp = blockIdx.x;   // 0..7
  const int tid = threadIdx.x, lane = tid & 63, wid = tid >> 6;
  const int l15 = lane & 15, lg = lane >> 4;

  __shared__ u16 Kl[2][64 * 64];   // [kv][hd], XOR-swizzled 16B slots
  __shared__ u16 Vt[2][64 * 64];   // [hd][kv], XOR-swizzled 16B slots
  __shared__ u16 Pl[8][16 * 72];   // per-wave P, stride 72 (144B, 16B-aligned)

  const size_t base = (size_t)bh * 2048 * 64;
  const u16* Qb = Q + base;
  const u16* Kb = K + base;
  const u16* Vb = V + base;

  const int qrow[2] = {qp * 128 + wid * 16, (15 - qp) * 128 + wid * 16};
  const int Thi = 2 * (15 - qp) + 2;

  // Q fragments (pre-scaled by 0.125*log2e in the QKV epilogue)
  short8 qf[2][2];
#pragma unroll
  for (int X = 0; X < 2; ++X)
#pragma unroll
    for (int ks = 0; ks < 2; ++ks)
      qf[X][ks] = *(const short8*)(Qb + (size_t)(qrow[X] + l15) * 64 + ks * 32 + lg * 8);

  f32x4 acc_o[2][4] = {};
  float mrun[2][4], lrun[2][4];
#pragma unroll
  for (int X = 0; X < 2; ++X)
#pragma unroll
    for (int j = 0; j < 4; ++j) { mrun[X][j] = -1e30f; lrun[X][j] = 0.f; }

  // staging geometry
  const int krow = tid >> 3, kslot = (tid & 7) ^ (krow & 7);  // K: 16B/thread
  const int vhd = lane, vkv0 = wid * 8;                        // V: 8 kv x 1 hd per thread

  // prologue: stage tile 0
  gload16(Kb + (size_t)krow * 64 + kslot * 8, &Kl[0][0] + wid * 512);
  {
    short8 vv;
#pragma unroll
    for (int j = 0; j < 8; ++j) vv[j] = (short)Vb[(size_t)(vkv0 + j) * 64 + vhd];
    *(short8*)((char*)&Vt[0][0] + vhd * 128 + ((wid ^ (vhd & 7)) << 4)) = vv;
  }
  __syncthreads();

  for (int t = 0; t < Thi; ++t) {
    const int cur = t & 1;
    const int kvb = t * 64;
    const bool pfn = (t + 1 < Thi);
    short8 vv;
    if (pfn) {  // issue next tile's staging early (T14): latency hides under compute
      const size_t nb = (size_t)(t + 1) * 64 * 64;
      gload16(Kb + nb + (size_t)krow * 64 + kslot * 8, &Kl[cur ^ 1][0] + wid * 512);
#pragma unroll
      for (int j = 0; j < 8; ++j) vv[j] = (short)Vb[nb + (size_t)(vkv0 + j) * 64 + vhd];
    }

    // K / V^T fragments for this tile (shared by both q-strips)
    short8 kf[4][2], vf[4][2];
#pragma unroll
    for (int n = 0; n < 4; ++n)
#pragma unroll
      for (int ks = 0; ks < 2; ++ks) {
        const int row = n * 16 + l15;
        const int swz = ((ks * 4 + lg) ^ (row & 7)) << 4;
        kf[n][ks] = *(const short8*)((const char*)&Kl[cur][0] + row * 128 + swz);
        vf[n][ks] = *(const short8*)((const char*)&Vt[cur][0] + row * 128 + swz);
      }

#pragma unroll
    for (int X = 0; X < 2; ++X) {
      if (kvb <= qrow[X] + 15) {  // wave-uniform: strip still has work in this tile
        f32x4 sa[4] = {};
#pragma unroll
        for (int n = 0; n < 4; ++n)
#pragma unroll
          for (int ks = 0; ks < 2; ++ks)
            sa[n] = __builtin_amdgcn_mfma_f32_16x16x32_bf16(qf[X][ks], kf[n][ks], sa[n], 0, 0, 0);
        if (kvb + 63 > qrow[X]) {
#pragma unroll
          for (int n = 0; n < 4; ++n)
#pragma unroll
            for (int j = 0; j < 4; ++j) {
              const int q = qrow[X] + lg * 4 + j;
              const int kv = kvb + n * 16 + l15;
              if (kv > q) sa[n][j] = -1e30f;
            }
        }
        float rm[4];
#pragma unroll
        for (int j = 0; j < 4; ++j) {
          rm[j] = fmaxf(fmaxf(sa[0][j], sa[1][j]), fmaxf(sa[2][j], sa[3][j]));
          rm[j] = fmaxf(rm[j], __shfl_xor(rm[j], 1));
          rm[j] = fmaxf(rm[j], __shfl_xor(rm[j], 2));
          rm[j] = fmaxf(rm[j], __shfl_xor(rm[j], 4));
          rm[j] = fmaxf(rm[j], __shfl_xor(rm[j], 8));
        }
#pragma unroll
        for (int j = 0; j < 4; ++j) {
          const float mnew = fmaxf(mrun[X][j], rm[j]);
          const float corr = exp2f(mrun[X][j] - mnew);
          mrun[X][j] = mnew;
          lrun[X][j] *= corr;
#pragma unroll
          for (int n = 0; n < 4; ++n) acc_o[X][n][j] *= corr;
        }
        float rs[4] = {0.f, 0.f, 0.f, 0.f};
#pragma unroll
        for (int n = 0; n < 4; ++n)
#pragma unroll
          for (int j = 0; j < 4; ++j) {
            const float p = exp2f(sa[n][j] - mrun[X][j]);
            sa[n][j] = p;
            rs[j] += p;
          }
#pragma unroll
        for (int j = 0; j < 4; ++j) {
          rs[j] += __shfl_xor(rs[j], 1);
          rs[j] += __shfl_xor(rs[j], 2);
          rs[j] += __shfl_xor(rs[j], 4);
          rs[j] += __shfl_xor(rs[j], 8);
          lrun[X][j] += rs[j];
        }
#pragma unroll
        for (int n = 0; n < 4; ++n)
#pragma unroll
          for (int j = 0; j < 4; ++j)
            Pl[wid][(lg * 4 + j) * 72 + n * 16 + l15] = f2bf(sa[n][j]);
        // PV
        short8 pf[2];
#pragma unroll
        for (int ks = 0; ks < 2; ++ks)
          pf[ks] = *(const short8*)((const char*)&Pl[wid][0] + l15 * 144 + ks * 64 + lg * 16);
#pragma unroll
        for (int n = 0; n < 4; ++n)
#pragma unroll
          for (int ks = 0; ks < 2; ++ks)
            acc_o[X][n] = __builtin_amdgcn_mfma_f32_16x16x32_bf16(pf[ks], vf[n][ks], acc_o[X][n], 0, 0, 0);
      }
    }

    if (pfn)  // late write of prefetched V into the other buffer
      *(short8*)((char*)&Vt[cur ^ 1][0] + vhd * 128 + ((wid ^ (vhd & 7)) << 4)) = vv;
    __syncthreads();
  }

  const int b = bh >> 4, h = bh & 15;
#pragma unroll
  for (int X = 0; X < 2; ++X)
#pragma unroll
    for (int n = 0; n < 4; ++n)
#pragma unroll
      for (int j = 0; j < 4; ++j) {
        const int q = qrow[X] + lg * 4 + j;
        const float v = acc_o[X][n][j] / lrun[X][j];
        Aout[(size_t)(b * 2048 + q) * 1024 + h * 64 + n * 16 + l15] = f2bf(v);
      }
}

extern "C" void kernel_launch(void* const* d_in, const int* in_sizes, int n_in,
                              void* d_out, int out_size, void* d_ws, size_t ws_size,
                              hipStream_t stream) {
  const float* x = (const float*)d_in[0];
  const float* Wqkv = (const float*)d_in[1];
  const float* bqkv = (const float*)d_in[2];
  const float* Wout = (const float*)d_in[3];
  const float* bout = (const float*)d_in[4];

  char* ws = (char*)d_ws;
  u16* Xb = (u16*)(ws + 0);            // 8,388,608 B  (reused as Attn later)
  u16* WqkvT = (u16*)(ws + 8388608);   // 6,291,456 B
  u16* WoutT = (u16*)(ws + 14680064);  // 2,097,152 B
  u16* QKV = (u16*)(ws + 16777216);    // 25,165,824 B
  u16* Attn = Xb;

  cvt_x_kernel<<<4096, 256, 0, stream>>>(x, Xb, 4194304);
  tcvt_kernel<<<dim3(96, 32), dim3(32, 8), 0, stream>>>(Wqkv, WqkvT, 3072);
  tcvt_kernel<<<dim3(32, 32), dim3(32, 8), 0, stream>>>(Wout, WoutT, 1024);
  gemm_kernel<0><<<dim3(24, 32), 256, 0, stream>>>(Xb, WqkvT, bqkv, QKV);
  attn_kernel<<<dim3(8, 32), 512, 0, stream>>>(QKV, QKV + 4194304, QKV + 8388608, Attn);
  gemm_kernel<1><<<dim3(8, 32), 256, 0, stream>>>(Attn, WoutT, bout, d_out);
}

// Round 3
// 133.371 us; speedup vs baseline: 1.3518x; 1.0822x over previous
//
#include <hip/hip_runtime.h>
#include <hip/hip_bf16.h>

typedef __attribute__((ext_vector_type(8))) short short8;
typedef __attribute__((ext_vector_type(4))) float f32x4;
typedef unsigned short u16;

__device__ __forceinline__ u16 f2bf(float f) {
  __hip_bfloat16 h = __float2bfloat16(f);
  return __builtin_bit_cast(unsigned short, h);
}

__device__ __forceinline__ void gload16(const u16* g, u16* l) {
  __builtin_amdgcn_global_load_lds(
      (const __attribute__((address_space(1))) unsigned int*)g,
      (__attribute__((address_space(3))) unsigned int*)l, 16, 0, 0);
}

// ---------- x fp32 -> bf16 ----------
__global__ void cvt_x_kernel(const float* __restrict__ in, u16* __restrict__ out, int n) {
  int i = (blockIdx.x * blockDim.x + threadIdx.x) * 4;
  if (i >= n) return;
  float4 f = *(const float4*)(in + i);
  uint2 pk;
  pk.x = (unsigned)f2bf(f.x) | ((unsigned)f2bf(f.y) << 16);
  pk.y = (unsigned)f2bf(f.z) | ((unsigned)f2bf(f.w) << 16);
  *(uint2*)(out + i) = pk;
}

// ---------- W [1024][N] fp32 -> Wt [N][1024] bf16 ----------
__global__ void tcvt_kernel(const float* __restrict__ in, u16* __restrict__ out, int N) {
  __shared__ float tile[32][33];
  int n0 = blockIdx.x * 32, k0 = blockIdx.y * 32;
  int tx = threadIdx.x, ty = threadIdx.y;  // 32 x 8
#pragma unroll
  for (int r = 0; r < 4; ++r) {
    int k = ty + r * 8;
    tile[k][tx] = in[(size_t)(k0 + k) * N + n0 + tx];
  }
  __syncthreads();
#pragma unroll
  for (int r = 0; r < 4; ++r) {
    int n = ty + r * 8;
    out[(size_t)(n0 + n) * 1024 + k0 + tx] = f2bf(tile[tx][n]);
  }
}

// ---------- GEMM: C[128x128 tile] = A[M][1024] * Bt[N][1024]^T + bias ----------
// EPI 0: scatter to QKV bf16 [3][b][h][s][64], Q scaled by 0.125*log2(e)
// EPI 1: fp32 out [4096][1024] + bias
template <int EPI>
__global__ __launch_bounds__(256, 2) void gemm_kernel(const u16* __restrict__ A,
                                                      const u16* __restrict__ Bt,
                                                      const float* __restrict__ bias,
                                                      void* __restrict__ outp) {
  __shared__ u16 Al[128 * 64];
  __shared__ u16 Bl[128 * 64];
  const int tid = threadIdx.x;
  const int lane = tid & 63, wid = tid >> 6;
  const int l15 = lane & 15, lg = lane >> 4;
  const int wm = wid >> 1, wn = wid & 1;
  const int m0 = blockIdx.y * 128, n0 = blockIdx.x * 128;

  f32x4 acc[4][4] = {};

  for (int k0 = 0; k0 < 1024; k0 += 64) {
    __syncthreads();
#pragma unroll
    for (int i = 0; i < 4; ++i) {
      int p = i * 4096 + tid * 16;
      int row = p >> 7;                         // tile row (128B per row)
      int lslot = ((p >> 4) & 7) ^ (row & 7);   // source pre-swizzle (T2)
      gload16(A + (size_t)(m0 + row) * 1024 + k0 + lslot * 8, Al + i * 2048 + wid * 512);
      gload16(Bt + (size_t)(n0 + row) * 1024 + k0 + lslot * 8, Bl + i * 2048 + wid * 512);
    }
    __syncthreads();
#pragma unroll
    for (int ks = 0; ks < 2; ++ks) {
      short8 af[4], bfr[4];
#pragma unroll
      for (int m = 0; m < 4; ++m) {
        int row = wm * 64 + m * 16 + l15;
        af[m] = *(const short8*)((const char*)Al + row * 128 + (((ks * 4 + lg) ^ (row & 7)) << 4));
      }
#pragma unroll
      for (int n = 0; n < 4; ++n) {
        int row = wn * 64 + n * 16 + l15;
        bfr[n] = *(const short8*)((const char*)Bl + row * 128 + (((ks * 4 + lg) ^ (row & 7)) << 4));
      }
#pragma unroll
      for (int m = 0; m < 4; ++m)
#pragma unroll
        for (int n = 0; n < 4; ++n)
          acc[m][n] = __builtin_amdgcn_mfma_f32_16x16x32_bf16(af[m], bfr[n], acc[m][n], 0, 0, 0);
    }
  }

  if (EPI == 0) {
    u16* qkv = (u16*)outp;
#pragma unroll
    for (int m = 0; m < 4; ++m)
#pragma unroll
      for (int n = 0; n < 4; ++n) {
        const int gcol = n0 + wn * 64 + n * 16 + l15;
        const int which = gcol >> 10, dd = gcol & 1023;
        const int h = dd >> 6, hd = dd & 63;
        const float bb = bias[gcol];
#pragma unroll
        for (int j = 0; j < 4; ++j) {
          const int grow = m0 + wm * 64 + m * 16 + lg * 4 + j;
          const int b = grow >> 11, s = grow & 2047;
          float v = acc[m][n][j] + bb;
          if (which == 0) v *= 0.18033688011112042f;  // 1/sqrt(64) * log2(e)
          qkv[(size_t)which * 4194304 + ((size_t)(b * 16 + h) * 2048 + s) * 64 + hd] = f2bf(v);
        }
      }
  } else {
    float* O = (float*)outp;
#pragma unroll
    for (int m = 0; m < 4; ++m)
#pragma unroll
      for (int n = 0; n < 4; ++n) {
        const int gcol = n0 + wn * 64 + n * 16 + l15;
        const float bb = bias[gcol];
#pragma unroll
        for (int j = 0; j < 4; ++j) {
          const int grow = m0 + wm * 64 + m * 16 + lg * 4 + j;
          O[(size_t)grow * 1024 + gcol] = acc[m][n][j] + bb;
        }
      }
  }
}

// ---------- causal flash attention ----------
// Grid (16, 32). Block = 256 threads (4 waves). Block p handles 64-row q-tiles
// p and 31-p (complement pairing -> exactly 33 tile-units per block).
// Wave w owns rows tile*64 + w*16 .. +15 of each q-tile.
// KV tiles double-buffered; next tile prefetched before computing current.
// Row-sum of P computed by MFMA against a ones matrix (acc_l); rescale deferred
// until the running max grows by >THR (T13).
__global__ __launch_bounds__(256, 2) void attn_kernel(const u16* __restrict__ Q,
                                                      const u16* __restrict__ K,
                                                      const u16* __restrict__ V,
                                                      u16* __restrict__ Aout) {
  const int bh = blockIdx.y;   // 0..31
  const int qp = blockIdx.x;   // 0..15
  const int tid = threadIdx.x, lane = tid & 63, wid = tid >> 6;
  const int l15 = lane & 15, lg = lane >> 4;

  __shared__ u16 Kl[2][64 * 64];   // [kv][hd], XOR-swizzled 16B slots
  __shared__ u16 Vt[2][64 * 64];   // [hd][kv], XOR-swizzled 16B slots
  __shared__ u16 Pl[4][16 * 72];   // per-wave P, stride 72 (144B, 16B-aligned)

  const size_t base = (size_t)bh * 2048 * 64;
  const u16* Qb = Q + base;
  const u16* Kb = K + base;
  const u16* Vb = V + base;

  const int qrow[2] = {qp * 64 + wid * 16, (31 - qp) * 64 + wid * 16};
  const int Thi = 32 - qp;  // t1 = 31-qp needs kv tiles 0..31-qp

  // Q fragments (pre-scaled by 0.125*log2e in the QKV epilogue)
  short8 qf[2][2];
#pragma unroll
  for (int X = 0; X < 2; ++X)
#pragma unroll
    for (int ks = 0; ks < 2; ++ks)
      qf[X][ks] = *(const short8*)(Qb + (size_t)(qrow[X] + l15) * 64 + ks * 32 + lg * 8);

  // ones fragment for row-sum MFMA (bf16 1.0 = 0x3F80)
  short8 onesf;
#pragma unroll
  for (int j = 0; j < 8; ++j) onesf[j] = (short)0x3F80;

  f32x4 acc_o[2][4] = {};
  f32x4 acc_l[2] = {};  // row-sum accumulator (all 16 cols equal per row)
  float mrun[2][4];
#pragma unroll
  for (int X = 0; X < 2; ++X)
#pragma unroll
    for (int j = 0; j < 4; ++j) mrun[X][j] = -1e30f;

  // staging geometry
  const int krow = tid >> 3, kslot = (tid & 7) ^ (krow & 7);  // K: 16B/thread x2 passes
  const int vhd = lane, vkv0 = wid * 16;                       // V: 16 kv x 1 hd per thread

  // prologue: stage tile 0
#pragma unroll
  for (int i = 0; i < 2; ++i)
    gload16(Kb + (size_t)(i * 32 + krow) * 64 + kslot * 8, &Kl[0][0] + i * 2048 + wid * 512);
  {
    short8 vv0, vv1;
#pragma unroll
    for (int j = 0; j < 8; ++j) {
      vv0[j] = (short)Vb[(size_t)(vkv0 + j) * 64 + vhd];
      vv1[j] = (short)Vb[(size_t)(vkv0 + 8 + j) * 64 + vhd];
    }
    *(short8*)((char*)&Vt[0][0] + vhd * 128 + (((wid * 2) ^ (vhd & 7)) << 4)) = vv0;
    *(short8*)((char*)&Vt[0][0] + vhd * 128 + (((wid * 2 + 1) ^ (vhd & 7)) << 4)) = vv1;
  }
  __syncthreads();

  for (int t = 0; t < Thi; ++t) {
    const int cur = t & 1;
    const int kvb = t * 64;
    const bool pfn = (t + 1 < Thi);
    short8 vv0, vv1;
    if (pfn) {  // issue next tile's staging early: latency hides under compute
      const size_t nb = (size_t)(t + 1) * 64 * 64;
#pragma unroll
      for (int i = 0; i < 2; ++i)
        gload16(Kb + nb + (size_t)(i * 32 + krow) * 64 + kslot * 8,
                &Kl[cur ^ 1][0] + i * 2048 + wid * 512);
#pragma unroll
      for (int j = 0; j < 8; ++j) {
        vv0[j] = (short)Vb[nb + (size_t)(vkv0 + j) * 64 + vhd];
        vv1[j] = (short)Vb[nb + (size_t)(vkv0 + 8 + j) * 64 + vhd];
      }
    }

    // K / V^T fragments for this tile (shared by both q-strips)
    short8 kf[4][2], vf[4][2];
#pragma unroll
    for (int n = 0; n < 4; ++n)
#pragma unroll
      for (int ks = 0; ks < 2; ++ks) {
        const int row = n * 16 + l15;
        const int swz = ((ks * 4 + lg) ^ (row & 7)) << 4;
        kf[n][ks] = *(const short8*)((const char*)&Kl[cur][0] + row * 128 + swz);
        vf[n][ks] = *(const short8*)((const char*)&Vt[cur][0] + row * 128 + swz);
      }

#pragma unroll
    for (int X = 0; X < 2; ++X) {
      if (kvb <= qrow[X] + 15) {  // wave-uniform: strip still has work in this tile
        f32x4 sa[4] = {};
#pragma unroll
        for (int n = 0; n < 4; ++n)
#pragma unroll
          for (int ks = 0; ks < 2; ++ks)
            sa[n] = __builtin_amdgcn_mfma_f32_16x16x32_bf16(qf[X][ks], kf[n][ks], sa[n], 0, 0, 0);
        if (kvb + 63 > qrow[X]) {
#pragma unroll
          for (int n = 0; n < 4; ++n)
#pragma unroll
            for (int j = 0; j < 4; ++j) {
              const int q = qrow[X] + lg * 4 + j;
              const int kv = kvb + n * 16 + l15;
              if (kv > q) sa[n][j] = -1e30f;
            }
        }
        float rm[4];
#pragma unroll
        for (int j = 0; j < 4; ++j) {
          rm[j] = fmaxf(fmaxf(sa[0][j], sa[1][j]), fmaxf(sa[2][j], sa[3][j]));
          rm[j] = fmaxf(rm[j], __shfl_xor(rm[j], 1));
          rm[j] = fmaxf(rm[j], __shfl_xor(rm[j], 2));
          rm[j] = fmaxf(rm[j], __shfl_xor(rm[j], 4));
          rm[j] = fmaxf(rm[j], __shfl_xor(rm[j], 8));
        }
        // T13 defer-max: only rescale when some row max grew by > THR (log2 units)
        bool ok = true;
#pragma unroll
        for (int j = 0; j < 4; ++j) ok &= (rm[j] <= mrun[X][j] + 5.0f);
        if (!__all(ok)) {
#pragma unroll
          for (int j = 0; j < 4; ++j) {
            const float mnew = fmaxf(mrun[X][j], rm[j]);
            const float corr = exp2f(mrun[X][j] - mnew);
            mrun[X][j] = mnew;
            acc_l[X][j] *= corr;
#pragma unroll
            for (int n = 0; n < 4; ++n) acc_o[X][n][j] *= corr;
          }
        }
#pragma unroll
        for (int n = 0; n < 4; ++n)
#pragma unroll
          for (int j = 0; j < 4; ++j)
            Pl[wid][(lg * 4 + j) * 72 + n * 16 + l15] = f2bf(exp2f(sa[n][j] - mrun[X][j]));
        // PV + row-sum (ones column trick)
        short8 pf[2];
#pragma unroll
        for (int ks = 0; ks < 2; ++ks)
          pf[ks] = *(const short8*)((const char*)&Pl[wid][0] + l15 * 144 + ks * 64 + lg * 16);
#pragma unroll
        for (int ks = 0; ks < 2; ++ks) {
          acc_l[X] = __builtin_amdgcn_mfma_f32_16x16x32_bf16(pf[ks], onesf, acc_l[X], 0, 0, 0);
#pragma unroll
          for (int n = 0; n < 4; ++n)
            acc_o[X][n] = __builtin_amdgcn_mfma_f32_16x16x32_bf16(pf[ks], vf[n][ks], acc_o[X][n], 0, 0, 0);
        }
      }
    }

    if (pfn) {  // late write of prefetched V into the other buffer
      *(short8*)((char*)&Vt[cur ^ 1][0] + vhd * 128 + (((wid * 2) ^ (vhd & 7)) << 4)) = vv0;
      *(short8*)((char*)&Vt[cur ^ 1][0] + vhd * 128 + (((wid * 2 + 1) ^ (vhd & 7)) << 4)) = vv1;
    }
    __syncthreads();
  }

  const int b = bh >> 4, h = bh & 15;
#pragma unroll
  for (int X = 0; X < 2; ++X) {
    float inv[4];
#pragma unroll
    for (int j = 0; j < 4; ++j) inv[j] = 1.0f / acc_l[X][j];
#pragma unroll
    for (int n = 0; n < 4; ++n)
#pragma unroll
      for (int j = 0; j < 4; ++j) {
        const int q = qrow[X] + lg * 4 + j;
        Aout[(size_t)(b * 2048 + q) * 1024 + h * 64 + n * 16 + l15] = f2bf(acc_o[X][n][j] * inv[j]);
      }
  }
}

extern "C" void kernel_launch(void* const* d_in, const int* in_sizes, int n_in,
                              void* d_out, int out_size, void* d_ws, size_t ws_size,
                              hipStream_t stream) {
  const float* x = (const float*)d_in[0];
  const float* Wqkv = (const float*)d_in[1];
  const float* bqkv = (const float*)d_in[2];
  const float* Wout = (const float*)d_in[3];
  const float* bout = (const float*)d_in[4];

  char* ws = (char*)d_ws;
  u16* Xb = (u16*)(ws + 0);            // 8,388,608 B  (reused as Attn later)
  u16* WqkvT = (u16*)(ws + 8388608);   // 6,291,456 B
  u16* WoutT = (u16*)(ws + 14680064);  // 2,097,152 B
  u16* QKV = (u16*)(ws + 16777216);    // 25,165,824 B
  u16* Attn = Xb;

  cvt_x_kernel<<<4096, 256, 0, stream>>>(x, Xb, 4194304);
  tcvt_kernel<<<dim3(96, 32), dim3(32, 8), 0, stream>>>(Wqkv, WqkvT, 3072);
  tcvt_kernel<<<dim3(32, 32), dim3(32, 8), 0, stream>>>(Wout, WoutT, 1024);
  gemm_kernel<0><<<dim3(24, 32), 256, 0, stream>>>(Xb, WqkvT, bqkv, QKV);
  attn_kernel<<<dim3(16, 32), 256, 0, stream>>>(QKV, QKV + 4194304, QKV + 8388608, Attn);
  gemm_kernel<1><<<dim3(8, 32), 256, 0, stream>>>(Attn, WoutT, bout, d_out);
}